// Round 7
// baseline (2216.868 us; speedup 1.0000x reference)
//
#include <hip/hip_runtime.h>

// ---------------------------------------------------------------------------
// 3-state pair-HMM forward DP (logsumexp semiring), skewed band pipeline v4.
//   12 bands x 128 rows; one 64-lane wave per band; lane L owns rows
//   128b+2L+1,+2 and computes a 2x2 cell block per step.
// R7: R3/R5/R6 proved staging latency is NOT the limiter (three different
//   prefetch structures, same ~1600 us). Suspects: (A) DPM downclock (12
//   waves on 256 CUs looks idle -> SCLK parks ~300-400 MHz; explains the
//   code-invariant ~6x vs cycle model); (B) agent-scope fence cost
//   (buffer_wbl2/buffer_inv per publish/poll on non-coherent XCD L2s).
//   Fixes: 244 FMA-heater blocks keep the chip busy until a done flag
//   (forces DPM to max clock); publish/poll cadence 16->32 steps (4x fewer
//   cache-maintenance events); vmcnt corrected 38->36 (exact drain of the
//   distance-4 global_load_lds batch for the 9-op band-0 case).
// ---------------------------------------------------------------------------

#define MM    1536
#define NB    12
#define GRID  256                 // 12 DP bands + 244 heater blocks
#define MP    768                 // column pairs per row
#define STEPS 832                 // 104 blocks * 8 steps; last active t = 830
#define TBLK  104
#define NSLOT 8
#define SLOTB 9248                // 9216 theta + 32 feed
#define DIST  4
#define LOG2E 1.4426950408889634f
#define LN2   0.6931471805599453f
#define NEG2  (-1.4426950408889634e8f)   // (-1e8)*LOG2E, log2-domain -inf

#define PK_BYTES  ((size_t)NB * STEPS * 64 * 36 * 4)   // 91,963,392
#define BOT_BYTES ((size_t)NB * (MM + 1) * 4 * 4)      // 295,104

// s_waitcnt imm: vmcnt=n (6-bit split), lgkmcnt/expcnt unconstrained
#define VMCNT_IMM(n) ((((n) >> 4) << 14) | 0x0F00 | 0x0070 | ((n) & 0xF))

static __device__ __forceinline__ float lse3_2(float a, float b, float c) {
    float mx = fmaxf(fmaxf(a, b), c);
    float mn = fminf(fminf(a, b), c);
    float md = __builtin_amdgcn_fmed3f(a, b, c);
    return mx + __builtin_amdgcn_logf(1.0f + __builtin_amdgcn_exp2f(mn - mx)
                                           + __builtin_amdgcn_exp2f(md - mx));
}

static __device__ __forceinline__ void gl_lds16(const void* g, void* l) {
    __builtin_amdgcn_global_load_lds(
        (const __attribute__((address_space(1))) void*)g,
        (__attribute__((address_space(3))) void*)l, 16, 0, 0);
}

__global__ void init_progress_kernel(int* progress) {
    if (threadIdx.x < NB) progress[threadIdx.x] = -1;
    if (threadIdx.x == NB) progress[NB] = 0;          // done flag
    if (threadIdx.x == NB + 1) progress[NB + 1] = 0;  // heater sink
}

// packed[((b*STEPS+t)*64+L)*36]: theta for (m = t-L):
//  [0..8] th[rowA-1][2m] | [9..17] th[rowA-1][2m+1]
//  [18..26] th[rowB-1][2m] | [27..35] th[rowB-1][2m+1],
//  rowA-1 = 128b+2L, rowB-1 = 128b+2L+1 (0-indexed theta rows).
__global__ __launch_bounds__(64)
void pack_kernel(const float* __restrict__ theta, float* __restrict__ packed) {
    const int bt = blockIdx.x;
    const int b  = bt / STEPS;
    const int t  = bt - b * STEPS;
    const int L  = threadIdx.x;
    const int m  = t - L;
    float* dst = (float*)__builtin_assume_aligned(packed, 16)
                 + ((size_t)bt * 64 + L) * 36;
    if (m >= 0 && m < MP) {
        const int rA0 = b * 128 + 2 * L;
        __builtin_memcpy(dst,      theta + ((size_t)rA0 * MM + 2 * m) * 9, 72);
        __builtin_memcpy(dst + 18, theta + ((size_t)(rA0 + 1) * MM + 2 * m) * 9, 72);
    } else {
        #pragma unroll
        for (int i = 0; i < 36; ++i) dst[i] = 0.0f;
    }
}

__global__ __launch_bounds__(64, 1)
void hmm_fwd_lds(const float* __restrict__ packed, float* __restrict__ out,
                 float* __restrict__ bottom, int* __restrict__ progress)
{
    __shared__ __align__(16) char lds[NSLOT * SLOTB];
    const int b = blockIdx.x;
    const int L = threadIdx.x;

    // ---------------- heater blocks: keep DPM at max clock -----------------
    if (b >= NB) {
        int* done = &progress[NB];
        float a0 = 1.0f + L, a1 = 2.0f, a2 = 3.0f, a3 = 4.0f;
        float a4 = 5.0f, a5 = 6.0f, a6 = 7.0f, a7 = 8.0f;
        bool run = true;
        while (run) {
            #pragma unroll 1
            for (int p = 0; p < 8 && run; ++p) {
                if (__hip_atomic_load(done, __ATOMIC_RELAXED,
                                      __HIP_MEMORY_SCOPE_AGENT)) run = false;
                #pragma unroll
                for (int i = 0; i < 64; ++i) {
                    a0 = fmaf(a0, 0.9999991f, 1e-7f);
                    a1 = fmaf(a1, 0.9999992f, 2e-7f);
                    a2 = fmaf(a2, 0.9999993f, 3e-7f);
                    a3 = fmaf(a3, 0.9999994f, 4e-7f);
                    a4 = fmaf(a4, 0.9999995f, 5e-7f);
                    a5 = fmaf(a5, 0.9999996f, 6e-7f);
                    a6 = fmaf(a6, 0.9999997f, 7e-7f);
                    a7 = fmaf(a7, 0.9999998f, 8e-7f);
                }
            }
            if (run && __hip_atomic_load(done, __ATOMIC_ACQUIRE,
                                         __HIP_MEMORY_SCOPE_AGENT)) run = false;
        }
        float s = a0 + a1 + a2 + a3 + a4 + a5 + a6 + a7;
        if (s == 123.4567891f)                  // never true; sinks the FMAs
            ((float*)progress)[NB + 1] = s;
        return;
    }

    // ---------------- DP bands --------------------------------------------
    const float* __restrict__ bsrc =
        bottom + (size_t)(b > 0 ? b - 1 : 0) * ((MM + 1) * 4);
    float* __restrict__ bdst = bottom + (size_t)b * ((MM + 1) * 4);

    // state (log2 domain): pd=V[rA-1][2m], pu1=V[rA-1][2m+1], pu2=V[rA-1][2m+2]
    //                      la=V[rA][2m], lb=V[rB][2m]
    float pd0, pd1, pd2, pu10, pu11, pu12, pu20, pu21, pu22;
    float la0, la1, la2, lb0, lb1, lb2, res0, res1, res2;
    pd0 = pd1 = pd2 = (b == 0 && L == 0) ? 0.0f : NEG2;   // V[0][0] = 0
    pu10 = pu11 = pu12 = NEG2;  pu20 = pu21 = pu22 = NEG2;
    la0 = la1 = la2 = NEG2;     lb0 = lb1 = lb2 = NEG2;
    res0 = res1 = res2 = NEG2;

    if (b > 0) {
        // cover prime (cols 1..2), initial batches and all feed issues until
        // the first in-loop poll at t0=32 (batch <= 35 -> col <= 74)
        while (__hip_atomic_load(&progress[b - 1], __ATOMIC_ACQUIRE,
                                 __HIP_MEMORY_SCOPE_AGENT) < 74)
            __builtin_amdgcn_s_sleep(2);
        float ta[4], tb[4];
        __builtin_memcpy(ta, bsrc + 4, 16);   // col 1
        __builtin_memcpy(tb, bsrc + 8, 16);   // col 2
        pu10 = (L == 0) ? ta[0] : NEG2;
        pu11 = (L == 0) ? ta[1] : NEG2;
        pu12 = (L == 0) ? ta[2] : NEG2;
        pu20 = (L == 0) ? tb[0] : NEG2;
        pu21 = (L == 0) ? tb[1] : NEG2;
        pu22 = (L == 0) ? tb[2] : NEG2;
    }

    // stage batch for step t (clamped): 9x16B theta (+1 feed for b>0)
    auto issue_batch = [&](int t) {
        int tc = t < STEPS ? t : STEPS - 1;
        const float* gp = packed + ((size_t)(b * STEPS + tc) * 64 + L) * 36;
        char* sb = lds + (size_t)(tc & (NSLOT - 1)) * SLOTB;
        #pragma unroll
        for (int c = 0; c < 9; ++c)
            gl_lds16(gp + c * 4, sb + c * 1024);
        if (b > 0 && L < 2) {
            int jn = 2 * tc + 3 + L;          // feed cols 2t+3, 2t+4
            if (jn > MM) jn = MM;
            gl_lds16(bsrc + (size_t)jn * 4, sb + 9216);
        }
    };

    issue_batch(0); issue_batch(1); issue_batch(2); issue_batch(3);

    for (int tb = 0; tb < TBLK; ++tb) {
        const int t0 = tb * 8;

        // producer publish every 32 steps (cols done through step t0-1)
        if (b < NB - 1 && t0 >= 64 && (t0 & 31) == 0 && L == 0) {
            int val = 2 * t0 - 126;
            if (val > MM) val = MM;
            __hip_atomic_store(&progress[b], val, __ATOMIC_RELEASE,
                               __HIP_MEMORY_SCOPE_AGENT);
        }
        // consumer poll every 32 steps: covers feed issues through batch
        // t0+31+DIST -> col 2*t0+74
        if (b > 0 && t0 > 0 && (t0 & 31) == 0) {
            int need = 2 * t0 + 74; if (need > MM) need = MM;
            while (__hip_atomic_load(&progress[b - 1], __ATOMIC_ACQUIRE,
                                     __HIP_MEMORY_SCOPE_AGENT) < need)
                __builtin_amdgcn_s_sleep(2);
        }

        #pragma unroll
        for (int k = 0; k < 8; ++k) {
            const int t = t0 + k;

            issue_batch(t + DIST);
            // <=36 outstanding: batch t (oldest) fully complete for both the
            // 9-op (b==0) and 10-op (b>0) batch sizes; batches t+1..t+4 in
            // flight. vmcnt is in-order -> the pipeline distance is explicit.
            __builtin_amdgcn_s_waitcnt(VMCNT_IMM(36));

            const char* sb = lds + (size_t)(t & (NSLOT - 1)) * SLOTB;
            float g[36];
            #pragma unroll
            for (int c = 0; c < 9; ++c) {
                float4 q = *(const float4*)(sb + c * 1024 + L * 16);
                g[c * 4 + 0] = q.x; g[c * 4 + 1] = q.y;
                g[c * 4 + 2] = q.z; g[c * 4 + 3] = q.w;
            }
            float4 ffa = *(const float4*)(sb + 9216);   // col 2t+3 (broadcast)
            float4 ffb = *(const float4*)(sb + 9232);   // col 2t+4

            const int m = t - L;
            const bool act = (m >= 0) && (m < MP);

            float x0, x1, x2;
            // A1 (rowA, col 2m+1): diag=pd, up=pu1, left=la
            x0 = fmaf(g[0], LOG2E, pd0);  x1 = fmaf(g[1], LOG2E, pd1);  x2 = fmaf(g[2], LOG2E, pd2);
            float nA1_0 = lse3_2(x0, x1, x2);
            x0 = fmaf(g[3], LOG2E, pu10); x1 = fmaf(g[4], LOG2E, pu11); x2 = fmaf(g[5], LOG2E, pu12);
            float nA1_1 = lse3_2(x0, x1, x2);
            x0 = fmaf(g[6], LOG2E, la0);  x1 = fmaf(g[7], LOG2E, la1);  x2 = fmaf(g[8], LOG2E, la2);
            float nA1_2 = lse3_2(x0, x1, x2);
            // A2 (rowA, col 2m+2): diag=pu1, up=pu2, left=nA1
            x0 = fmaf(g[9],  LOG2E, pu10); x1 = fmaf(g[10], LOG2E, pu11); x2 = fmaf(g[11], LOG2E, pu12);
            float nA2_0 = lse3_2(x0, x1, x2);
            x0 = fmaf(g[12], LOG2E, pu20); x1 = fmaf(g[13], LOG2E, pu21); x2 = fmaf(g[14], LOG2E, pu22);
            float nA2_1 = lse3_2(x0, x1, x2);
            x0 = fmaf(g[15], LOG2E, nA1_0); x1 = fmaf(g[16], LOG2E, nA1_1); x2 = fmaf(g[17], LOG2E, nA1_2);
            float nA2_2 = lse3_2(x0, x1, x2);
            // B1 (rowB, col 2m+1): diag=la, up=nA1, left=lb
            x0 = fmaf(g[18], LOG2E, la0);  x1 = fmaf(g[19], LOG2E, la1);  x2 = fmaf(g[20], LOG2E, la2);
            float nB1_0 = lse3_2(x0, x1, x2);
            x0 = fmaf(g[21], LOG2E, nA1_0); x1 = fmaf(g[22], LOG2E, nA1_1); x2 = fmaf(g[23], LOG2E, nA1_2);
            float nB1_1 = lse3_2(x0, x1, x2);
            x0 = fmaf(g[24], LOG2E, lb0);  x1 = fmaf(g[25], LOG2E, lb1);  x2 = fmaf(g[26], LOG2E, lb2);
            float nB1_2 = lse3_2(x0, x1, x2);
            // B2 (rowB, col 2m+2): diag=nA1, up=nA2, left=nB1
            x0 = fmaf(g[27], LOG2E, nA1_0); x1 = fmaf(g[28], LOG2E, nA1_1); x2 = fmaf(g[29], LOG2E, nA1_2);
            float nB2_0 = lse3_2(x0, x1, x2);
            x0 = fmaf(g[30], LOG2E, nA2_0); x1 = fmaf(g[31], LOG2E, nA2_1); x2 = fmaf(g[32], LOG2E, nA2_2);
            float nB2_1 = lse3_2(x0, x1, x2);
            x0 = fmaf(g[33], LOG2E, nB1_0); x1 = fmaf(g[34], LOG2E, nB1_1); x2 = fmaf(g[35], LOG2E, nB1_2);
            float nB2_2 = lse3_2(x0, x1, x2);

            // mask escaping values
            nA2_0 = act ? nA2_0 : NEG2; nA2_1 = act ? nA2_1 : NEG2; nA2_2 = act ? nA2_2 : NEG2;
            nB1_0 = act ? nB1_0 : NEG2; nB1_1 = act ? nB1_1 : NEG2; nB1_2 = act ? nB1_2 : NEG2;
            nB2_0 = act ? nB2_0 : NEG2; nB2_1 = act ? nB2_1 : NEG2; nB2_2 = act ? nB2_2 : NEG2;

            // producer: lane 63's rowB is the band's bottom row
            if (b < NB - 1 && L == 63 && act) {
                float st[8] = {nB1_0, nB1_1, nB1_2, 0.0f,
                               nB2_0, nB2_1, nB2_2, 0.0f};
                __builtin_memcpy(bdst + (size_t)(2 * m + 1) * 4, st, 32);
            }
            if (b == NB - 1) {
                const bool fin = (L == 63) && (t == 830);   // m = 767
                res0 = fin ? nB2_0 : res0;
                res1 = fin ? nB2_1 : res1;
                res2 = fin ? nB2_2 : res2;
            }

            // rotate state for step t+1
            float opu20 = pu20, opu21 = pu21, opu22 = pu22;
            float s0 = __shfl_up(nB1_0, 1, 64);
            float s1 = __shfl_up(nB1_1, 1, 64);
            float s2 = __shfl_up(nB1_2, 1, 64);
            float s3 = __shfl_up(nB2_0, 1, 64);
            float s4 = __shfl_up(nB2_1, 1, 64);
            float s5 = __shfl_up(nB2_2, 1, 64);
            pu10 = (L == 0) ? (b > 0 ? ffa.x : NEG2) : s0;
            pu11 = (L == 0) ? (b > 0 ? ffa.y : NEG2) : s1;
            pu12 = (L == 0) ? (b > 0 ? ffa.z : NEG2) : s2;
            pu20 = (L == 0) ? (b > 0 ? ffb.x : NEG2) : s3;
            pu21 = (L == 0) ? (b > 0 ? ffb.y : NEG2) : s4;
            pu22 = (L == 0) ? (b > 0 ? ffb.z : NEG2) : s5;
            pd0 = opu20; pd1 = opu21; pd2 = opu22;
            la0 = nA2_0; la1 = nA2_1; la2 = nA2_2;
            lb0 = nB2_0; lb1 = nB2_1; lb2 = nB2_2;
        }
    }

    if (b < NB - 1) {
        if (L == 0)
            __hip_atomic_store(&progress[b], MM, __ATOMIC_RELEASE,
                               __HIP_MEMORY_SCOPE_AGENT);
    } else if (L == 63) {
        out[0] = LN2 * lse3_2(res0, res1, res2);
        __hip_atomic_store(&progress[NB], 1, __ATOMIC_RELEASE,
                           __HIP_MEMORY_SCOPE_AGENT);   // stop the heaters
    }
}

extern "C" void kernel_launch(void* const* d_in, const int* in_sizes, int n_in,
                              void* d_out, int out_size, void* d_ws, size_t ws_size,
                              hipStream_t stream)
{
    const float* theta = (const float*)d_in[0];
    float* out = (float*)d_out;

    float* packed   = (float*)d_ws;
    float* bottom   = (float*)((char*)d_ws + PK_BYTES);
    int*   progress = (int*)((char*)d_ws + PK_BYTES + BOT_BYTES);

    init_progress_kernel<<<1, 64, 0, stream>>>(progress);
    pack_kernel<<<NB * STEPS, 64, 0, stream>>>(theta, packed);
    hmm_fwd_lds<<<GRID, 64, 0, stream>>>(packed, out, bottom, progress);
}

// Round 8
// 1834.233 us; speedup vs baseline: 1.2086x; 1.2086x over previous
//
#include <hip/hip_runtime.h>

// ---------------------------------------------------------------------------
// 3-state pair-HMM forward DP (logsumexp semiring), skewed band pipeline v5.
//   12 bands x 128 rows; one 64-lane wave per band; lane L owns rows
//   128b+2L+1,+2 and computes a 2x2 cell block per step. Theta pre-packed to
//   skew layout, staged via global_load_lds at distance 4 (un-sinkable).
// R8: R7's heater test was invalidated by false sharing - the done flag
//   shared a cache line with the DP progress flags; 244 waves hammering it
//   poisoned every DP poll (heater VALUBusy 15% not ~50% => ~5800cy/load).
//   Fixes: (1) every flag on its own 128B line; (2) relaxed-spin polls with
//   ONE acquire on exit (one buffer_inv per poll, not per iteration);
//   (3) publish cadence 8->16 (halves release-store vmcnt(0) pipeline
//   drains); (4) heaters poll their private line only every ~3.4us;
//   (5) vmcnt 36->40 restores full prefetch distance.
// ---------------------------------------------------------------------------

#define MM    1536
#define NB    12
#define GRID  256                 // 12 DP bands + 244 heater blocks
#define MP    768                 // column pairs per row
#define STEPS 832                 // 104 blocks * 8 steps; last active t = 830
#define TBLK  104
#define NSLOT 8
#define SLOTB 9248                // 9216 theta + 32 feed
#define DIST  4
#define LOG2E 1.4426950408889634f
#define LN2   0.6931471805599453f
#define NEG2  (-1.4426950408889634e8f)   // (-1e8)*LOG2E, log2-domain -inf

#define PK_BYTES  ((size_t)NB * STEPS * 64 * 36 * 4)   // 91,963,392
#define BOT_BYTES ((size_t)NB * (MM + 1) * 4 * 4)      // 295,104

#define FLAG(i) progress[(size_t)(i) * 32]             // one flag per 128B line

// s_waitcnt imm: vmcnt=n (6-bit split), lgkmcnt/expcnt unconstrained
#define VMCNT_IMM(n) ((((n) >> 4) << 14) | 0x0F00 | 0x0070 | ((n) & 0xF))

static __device__ __forceinline__ float lse3_2(float a, float b, float c) {
    float mx = fmaxf(fmaxf(a, b), c);
    float mn = fminf(fminf(a, b), c);
    float md = __builtin_amdgcn_fmed3f(a, b, c);
    return mx + __builtin_amdgcn_logf(1.0f + __builtin_amdgcn_exp2f(mn - mx)
                                           + __builtin_amdgcn_exp2f(md - mx));
}

static __device__ __forceinline__ void gl_lds16(const void* g, void* l) {
    __builtin_amdgcn_global_load_lds(
        (const __attribute__((address_space(1))) void*)g,
        (__attribute__((address_space(3))) void*)l, 16, 0, 0);
}

// relaxed spin until flag >= need, then one acquire load (syncs-with the
// release that published the satisfying value; flag is monotone)
static __device__ __forceinline__ void wait_flag(int* f, int need) {
    for (;;) {
        if (__hip_atomic_load(f, __ATOMIC_RELAXED,
                              __HIP_MEMORY_SCOPE_AGENT) >= need) {
            (void)__hip_atomic_load(f, __ATOMIC_ACQUIRE,
                                    __HIP_MEMORY_SCOPE_AGENT);
            return;
        }
        __builtin_amdgcn_s_sleep(2);
    }
}

__global__ void init_progress_kernel(int* progress) {
    if (threadIdx.x < NB) FLAG(threadIdx.x) = -1;
    if (threadIdx.x == NB) FLAG(NB) = 0;          // heater done flag
}

// packed[((b*STEPS+t)*64+L)*36]: theta for (m = t-L):
//  [0..8] th[rowA-1][2m] | [9..17] th[rowA-1][2m+1]
//  [18..26] th[rowB-1][2m] | [27..35] th[rowB-1][2m+1],
//  rowA-1 = 128b+2L, rowB-1 = 128b+2L+1 (0-indexed theta rows).
__global__ __launch_bounds__(64)
void pack_kernel(const float* __restrict__ theta, float* __restrict__ packed) {
    const int bt = blockIdx.x;
    const int b  = bt / STEPS;
    const int t  = bt - b * STEPS;
    const int L  = threadIdx.x;
    const int m  = t - L;
    float* dst = (float*)__builtin_assume_aligned(packed, 16)
                 + ((size_t)bt * 64 + L) * 36;
    if (m >= 0 && m < MP) {
        const int rA0 = b * 128 + 2 * L;
        __builtin_memcpy(dst,      theta + ((size_t)rA0 * MM + 2 * m) * 9, 72);
        __builtin_memcpy(dst + 18, theta + ((size_t)(rA0 + 1) * MM + 2 * m) * 9, 72);
    } else {
        #pragma unroll
        for (int i = 0; i < 36; ++i) dst[i] = 0.0f;
    }
}

__global__ __launch_bounds__(64, 1)
void hmm_fwd_lds(const float* __restrict__ packed, float* __restrict__ out,
                 float* __restrict__ bottom, int* __restrict__ progress)
{
    __shared__ __align__(16) char lds[NSLOT * SLOTB];
    const int b = blockIdx.x;
    const int L = threadIdx.x;

    // ------- heater blocks: hold SCLK at max; private line, rare polls -----
    if (b >= NB) {
        int* done = &FLAG(NB);
        float a0 = 1.0f + L, a1 = 2.0f + b * 0.001f, a2 = 3.0f, a3 = 4.0f;
        float a4 = 5.0f, a5 = 6.0f, a6 = 7.0f, a7 = 8.0f;
        for (;;) {
            #pragma unroll 4
            for (int i = 0; i < 512; ++i) {       // 4096 FMAs ~ 3.4 us
                a0 = fmaf(a0, 0.9999991f, 1e-7f);
                a1 = fmaf(a1, 0.9999992f, 2e-7f);
                a2 = fmaf(a2, 0.9999993f, 3e-7f);
                a3 = fmaf(a3, 0.9999994f, 4e-7f);
                a4 = fmaf(a4, 0.9999995f, 5e-7f);
                a5 = fmaf(a5, 0.9999996f, 6e-7f);
                a6 = fmaf(a6, 0.9999997f, 7e-7f);
                a7 = fmaf(a7, 0.9999998f, 8e-7f);
            }
            if (__hip_atomic_load(done, __ATOMIC_RELAXED,
                                  __HIP_MEMORY_SCOPE_AGENT)) break;
        }
        float s = a0 + a1 + a2 + a3 + a4 + a5 + a6 + a7;
        if (s == 123.4567891f)                    // never true; sinks the FMAs
            ((float*)progress)[(NB + 1) * 32] = s;
        return;
    }

    // ---------------- DP bands --------------------------------------------
    const float* __restrict__ bsrc =
        bottom + (size_t)(b > 0 ? b - 1 : 0) * ((MM + 1) * 4);
    float* __restrict__ bdst = bottom + (size_t)b * ((MM + 1) * 4);

    // state (log2 domain): pd=V[rA-1][2m], pu1=V[rA-1][2m+1], pu2=V[rA-1][2m+2]
    //                      la=V[rA][2m], lb=V[rB][2m]
    float pd0, pd1, pd2, pu10, pu11, pu12, pu20, pu21, pu22;
    float la0, la1, la2, lb0, lb1, lb2, res0, res1, res2;
    pd0 = pd1 = pd2 = (b == 0 && L == 0) ? 0.0f : NEG2;   // V[0][0] = 0
    pu10 = pu11 = pu12 = NEG2;  pu20 = pu21 = pu22 = NEG2;
    la0 = la1 = la2 = NEG2;     lb0 = lb1 = lb2 = NEG2;
    res0 = res1 = res2 = NEG2;

    if (b > 0) {
        // cover prime (cols 1..2) + all feed issues (col <= 42) until the
        // first in-loop poll at t0=16
        wait_flag(&FLAG(b - 1), 48);
        float ta[4], tb[4];
        __builtin_memcpy(ta, bsrc + 4, 16);   // col 1
        __builtin_memcpy(tb, bsrc + 8, 16);   // col 2
        pu10 = (L == 0) ? ta[0] : NEG2;
        pu11 = (L == 0) ? ta[1] : NEG2;
        pu12 = (L == 0) ? ta[2] : NEG2;
        pu20 = (L == 0) ? tb[0] : NEG2;
        pu21 = (L == 0) ? tb[1] : NEG2;
        pu22 = (L == 0) ? tb[2] : NEG2;
    }

    // stage batch for step t (clamped): 9x16B theta (+1 feed for b>0)
    auto issue_batch = [&](int t) {
        int tc = t < STEPS ? t : STEPS - 1;
        const float* gp = packed + ((size_t)(b * STEPS + tc) * 64 + L) * 36;
        char* sb = lds + (size_t)(tc & (NSLOT - 1)) * SLOTB;
        #pragma unroll
        for (int c = 0; c < 9; ++c)
            gl_lds16(gp + c * 4, sb + c * 1024);
        if (b > 0 && L < 2) {
            int jn = 2 * tc + 3 + L;          // feed cols 2t+3, 2t+4
            if (jn > MM) jn = MM;
            gl_lds16(bsrc + (size_t)jn * 4, sb + 9216);
        }
    };

    issue_batch(0); issue_batch(1); issue_batch(2); issue_batch(3);

    for (int tb = 0; tb < TBLK; ++tb) {
        const int t0 = tb * 8;

        // producer publish every 16 steps (release; its vmcnt(0) drain of the
        // staging pipeline is the main fence cost - amortized over 16 steps)
        if (b < NB - 1 && t0 >= 64 && (t0 & 15) == 0 && L == 0) {
            int val = 2 * t0 - 126;           // cols done through step t0-1
            if (val > MM) val = MM;
            __hip_atomic_store(&FLAG(b), val, __ATOMIC_RELEASE,
                               __HIP_MEMORY_SCOPE_AGENT);
        }
        // consumer poll every 16 steps: covers feed issues through col 2t0+42
        if (b > 0 && t0 > 0 && (t0 & 15) == 0) {
            int need = 2 * t0 + 42; if (need > MM) need = MM;
            wait_flag(&FLAG(b - 1), need);
        }

        #pragma unroll
        for (int k = 0; k < 8; ++k) {
            const int t = t0 + k;

            issue_batch(t + DIST);
            // <=40 outstanding: the 4 in-flight batches (t+1..t+4) hold 40
            // ops max, so batch t (issued 4 steps ago) is fully drained.
            __builtin_amdgcn_s_waitcnt(VMCNT_IMM(40));

            const char* sb = lds + (size_t)(t & (NSLOT - 1)) * SLOTB;
            float g[36];
            #pragma unroll
            for (int c = 0; c < 9; ++c) {
                float4 q = *(const float4*)(sb + c * 1024 + L * 16);
                g[c * 4 + 0] = q.x; g[c * 4 + 1] = q.y;
                g[c * 4 + 2] = q.z; g[c * 4 + 3] = q.w;
            }
            float4 ffa = *(const float4*)(sb + 9216);   // col 2t+3 (broadcast)
            float4 ffb = *(const float4*)(sb + 9232);   // col 2t+4

            const int m = t - L;
            const bool act = (m >= 0) && (m < MP);

            float x0, x1, x2;
            // A1 (rowA, col 2m+1): diag=pd, up=pu1, left=la
            x0 = fmaf(g[0], LOG2E, pd0);  x1 = fmaf(g[1], LOG2E, pd1);  x2 = fmaf(g[2], LOG2E, pd2);
            float nA1_0 = lse3_2(x0, x1, x2);
            x0 = fmaf(g[3], LOG2E, pu10); x1 = fmaf(g[4], LOG2E, pu11); x2 = fmaf(g[5], LOG2E, pu12);
            float nA1_1 = lse3_2(x0, x1, x2);
            x0 = fmaf(g[6], LOG2E, la0);  x1 = fmaf(g[7], LOG2E, la1);  x2 = fmaf(g[8], LOG2E, la2);
            float nA1_2 = lse3_2(x0, x1, x2);
            // A2 (rowA, col 2m+2): diag=pu1, up=pu2, left=nA1
            x0 = fmaf(g[9],  LOG2E, pu10); x1 = fmaf(g[10], LOG2E, pu11); x2 = fmaf(g[11], LOG2E, pu12);
            float nA2_0 = lse3_2(x0, x1, x2);
            x0 = fmaf(g[12], LOG2E, pu20); x1 = fmaf(g[13], LOG2E, pu21); x2 = fmaf(g[14], LOG2E, pu22);
            float nA2_1 = lse3_2(x0, x1, x2);
            x0 = fmaf(g[15], LOG2E, nA1_0); x1 = fmaf(g[16], LOG2E, nA1_1); x2 = fmaf(g[17], LOG2E, nA1_2);
            float nA2_2 = lse3_2(x0, x1, x2);
            // B1 (rowB, col 2m+1): diag=la, up=nA1, left=lb
            x0 = fmaf(g[18], LOG2E, la0);  x1 = fmaf(g[19], LOG2E, la1);  x2 = fmaf(g[20], LOG2E, la2);
            float nB1_0 = lse3_2(x0, x1, x2);
            x0 = fmaf(g[21], LOG2E, nA1_0); x1 = fmaf(g[22], LOG2E, nA1_1); x2 = fmaf(g[23], LOG2E, nA1_2);
            float nB1_1 = lse3_2(x0, x1, x2);
            x0 = fmaf(g[24], LOG2E, lb0);  x1 = fmaf(g[25], LOG2E, lb1);  x2 = fmaf(g[26], LOG2E, lb2);
            float nB1_2 = lse3_2(x0, x1, x2);
            // B2 (rowB, col 2m+2): diag=nA1, up=nA2, left=nB1
            x0 = fmaf(g[27], LOG2E, nA1_0); x1 = fmaf(g[28], LOG2E, nA1_1); x2 = fmaf(g[29], LOG2E, nA1_2);
            float nB2_0 = lse3_2(x0, x1, x2);
            x0 = fmaf(g[30], LOG2E, nA2_0); x1 = fmaf(g[31], LOG2E, nA2_1); x2 = fmaf(g[32], LOG2E, nA2_2);
            float nB2_1 = lse3_2(x0, x1, x2);
            x0 = fmaf(g[33], LOG2E, nB1_0); x1 = fmaf(g[34], LOG2E, nB1_1); x2 = fmaf(g[35], LOG2E, nB1_2);
            float nB2_2 = lse3_2(x0, x1, x2);

            // mask escaping values
            nA2_0 = act ? nA2_0 : NEG2; nA2_1 = act ? nA2_1 : NEG2; nA2_2 = act ? nA2_2 : NEG2;
            nB1_0 = act ? nB1_0 : NEG2; nB1_1 = act ? nB1_1 : NEG2; nB1_2 = act ? nB1_2 : NEG2;
            nB2_0 = act ? nB2_0 : NEG2; nB2_1 = act ? nB2_1 : NEG2; nB2_2 = act ? nB2_2 : NEG2;

            // producer: lane 63's rowB is the band's bottom row
            if (b < NB - 1 && L == 63 && act) {
                float st[8] = {nB1_0, nB1_1, nB1_2, 0.0f,
                               nB2_0, nB2_1, nB2_2, 0.0f};
                __builtin_memcpy(bdst + (size_t)(2 * m + 1) * 4, st, 32);
            }
            if (b == NB - 1) {
                const bool fin = (L == 63) && (t == 830);   // m = 767
                res0 = fin ? nB2_0 : res0;
                res1 = fin ? nB2_1 : res1;
                res2 = fin ? nB2_2 : res2;
            }

            // rotate state for step t+1
            float opu20 = pu20, opu21 = pu21, opu22 = pu22;
            float s0 = __shfl_up(nB1_0, 1, 64);
            float s1 = __shfl_up(nB1_1, 1, 64);
            float s2 = __shfl_up(nB1_2, 1, 64);
            float s3 = __shfl_up(nB2_0, 1, 64);
            float s4 = __shfl_up(nB2_1, 1, 64);
            float s5 = __shfl_up(nB2_2, 1, 64);
            pu10 = (L == 0) ? (b > 0 ? ffa.x : NEG2) : s0;
            pu11 = (L == 0) ? (b > 0 ? ffa.y : NEG2) : s1;
            pu12 = (L == 0) ? (b > 0 ? ffa.z : NEG2) : s2;
            pu20 = (L == 0) ? (b > 0 ? ffb.x : NEG2) : s3;
            pu21 = (L == 0) ? (b > 0 ? ffb.y : NEG2) : s4;
            pu22 = (L == 0) ? (b > 0 ? ffb.z : NEG2) : s5;
            pd0 = opu20; pd1 = opu21; pd2 = opu22;
            la0 = nA2_0; la1 = nA2_1; la2 = nA2_2;
            lb0 = nB2_0; lb1 = nB2_1; lb2 = nB2_2;
        }
    }

    if (b < NB - 1) {
        if (L == 0)
            __hip_atomic_store(&FLAG(b), MM, __ATOMIC_RELEASE,
                               __HIP_MEMORY_SCOPE_AGENT);
    } else if (L == 63) {
        out[0] = LN2 * lse3_2(res0, res1, res2);
        __hip_atomic_store(&FLAG(NB), 1, __ATOMIC_RELEASE,
                           __HIP_MEMORY_SCOPE_AGENT);   // stop the heaters
    }
}

extern "C" void kernel_launch(void* const* d_in, const int* in_sizes, int n_in,
                              void* d_out, int out_size, void* d_ws, size_t ws_size,
                              hipStream_t stream)
{
    const float* theta = (const float*)d_in[0];
    float* out = (float*)d_out;

    float* packed   = (float*)d_ws;
    float* bottom   = (float*)((char*)d_ws + PK_BYTES);
    int*   progress = (int*)((char*)d_ws + PK_BYTES + BOT_BYTES);

    init_progress_kernel<<<1, 64, 0, stream>>>(progress);
    pack_kernel<<<NB * STEPS, 64, 0, stream>>>(theta, packed);
    hmm_fwd_lds<<<GRID, 64, 0, stream>>>(packed, out, bottom, progress);
}